// Round 1
// baseline (153.665 us; speedup 1.0000x reference)
//
#include <hip/hip_runtime.h>
#include <cstdint>
#include <cstddef>

#define NEG_SLOPE 0.2f

__device__ __forceinline__ float leaky_f(float x) { return x >= 0.f ? x : NEG_SLOPE * x; }

// -------------------- generic tiled f32 GEMM: C = act(A @ W^T [+ b]) --------------------
// A [M,K] row-major, W [BN,K] row-major (BN == full output width), C [M,BN].
// MODE 0: leaky(acc + bias[col]);  MODE 1: acc;  MODE 2: q = 1/(1 + cn2[col] + hn2[row] - 2*acc)
template<int BM, int BN, int BK, int TM, int TN, int MODE>
__global__ __launch_bounds__(256)
void gemm_f32(const float* __restrict__ A, const float* __restrict__ W,
              const float* __restrict__ bias, float* __restrict__ Cout,
              int M, int K,
              const float* __restrict__ hn2, const float* __restrict__ cn2)
{
    constexpr int NTX = BN / TN;
    constexpr int NTY = BM / TM;
    static_assert(NTX * NTY == 256, "block must be 256 threads");
    static_assert(TM == 4, "A frag is one float4");

    __shared__ float As[BK][BM + 4];
    __shared__ float Bs[BK][BN + 4];

    const int tid = threadIdx.x;
    const int tx = tid % NTX;
    const int ty = tid / NTX;
    const int rowBlk = blockIdx.x * BM;

    float acc[TM][TN];
#pragma unroll
    for (int i = 0; i < TM; i++)
#pragma unroll
        for (int j = 0; j < TN; j++) acc[i][j] = 0.f;

    for (int k0 = 0; k0 < K; k0 += BK) {
        // stage A tile (BM x BK), transposed to k-major
        for (int i4 = tid; i4 < BM * BK / 4; i4 += 256) {
            int r  = i4 / (BK / 4);
            int kq = i4 % (BK / 4);
            float4 v = make_float4(0.f, 0.f, 0.f, 0.f);
            int gr = rowBlk + r;
            if (gr < M) v = *reinterpret_cast<const float4*>(A + (size_t)gr * K + k0 + kq * 4);
            As[kq * 4 + 0][r] = v.x;
            As[kq * 4 + 1][r] = v.y;
            As[kq * 4 + 2][r] = v.z;
            As[kq * 4 + 3][r] = v.w;
        }
        // stage B tile (BN x BK), transposed to k-major (always in-bounds)
        for (int i4 = tid; i4 < BN * BK / 4; i4 += 256) {
            int r  = i4 / (BK / 4);
            int kq = i4 % (BK / 4);
            float4 v = *reinterpret_cast<const float4*>(W + (size_t)r * K + k0 + kq * 4);
            Bs[kq * 4 + 0][r] = v.x;
            Bs[kq * 4 + 1][r] = v.y;
            Bs[kq * 4 + 2][r] = v.z;
            Bs[kq * 4 + 3][r] = v.w;
        }
        __syncthreads();
#pragma unroll
        for (int k = 0; k < BK; k++) {
            float a[TM], b[TN];
            *reinterpret_cast<float4*>(a) = *reinterpret_cast<const float4*>(&As[k][ty * TM]);
#pragma unroll
            for (int q = 0; q < TN / 4; q++)
                *reinterpret_cast<float4*>(b + 4 * q) =
                    *reinterpret_cast<const float4*>(&Bs[k][tx * TN + 4 * q]);
#pragma unroll
            for (int i = 0; i < TM; i++)
#pragma unroll
                for (int j = 0; j < TN; j++) acc[i][j] = fmaf(a[i], b[j], acc[i][j]);
        }
        __syncthreads();
    }

    // epilogue
#pragma unroll
    for (int i = 0; i < TM; i++) {
        int gr = rowBlk + ty * TM + i;
        if (gr >= M) continue;
        float vout[TN];
#pragma unroll
        for (int j = 0; j < TN; j++) {
            int col = tx * TN + j;
            float v = acc[i][j];
            if (MODE == 0)      v = leaky_f(v + bias[col]);
            else if (MODE == 2) v = 1.f / (1.f + cn2[col] + hn2[gr] - 2.f * v);
            vout[j] = v;
        }
#pragma unroll
        for (int q = 0; q < TN / 4; q++)
            *reinterpret_cast<float4*>(Cout + (size_t)gr * BN + tx * TN + 4 * q) =
                *reinterpret_cast<const float4*>(vout + 4 * q);
    }
}

// -------------------- row squared-norms: hn2[N] from h, cn2[64] from centroids --------------------
__global__ __launch_bounds__(256)
void norms_kernel(const float* __restrict__ h, const float* __restrict__ cent,
                  float* __restrict__ hn2, float* __restrict__ cn2, int N)
{
    const int wv = threadIdx.x >> 6;
    const int lane = threadIdx.x & 63;
    const int row = blockIdx.x * 4 + wv;
    const int total = N + 64;
    if (row >= total) return;
    const float* src = (row < N) ? (h + (size_t)row * 128) : (cent + (size_t)(row - N) * 128);
    float a = src[lane], b = src[lane + 64];
    float s = fmaf(a, a, b * b);
#pragma unroll
    for (int off = 32; off > 0; off >>= 1) s += __shfl_xor(s, off);
    if (lane == 0) {
        if (row < N) hn2[row] = s; else cn2[row - N] = s;
    }
}

// -------------------- per-node aggregation: one wave per node --------------------
// out1[n,c,d] = leaky( sum_e w[n,c,e] * hW[adj[n,e],d] + b21[d] )
// w = softmax_e( sum_h headConv[h] * q[adj[e]][h*16+c] / (sum_e' q[adj[e']][h*16+c]) )
__global__ __launch_bounds__(256)
void agg_kernel(const int* __restrict__ adj, const float* __restrict__ qt,
                const float* __restrict__ hW, const float* __restrict__ b21,
                const float* __restrict__ headConv, float* __restrict__ out1)
{
    __shared__ float qbuf[4][16][68];    // [wave][e][hc] (+pad)
    __shared__ float hbuf[4][16][136];   // [wave][e][d]  (+pad)
    __shared__ float wbuf[4][16][16];    // [wave][e][c]
    __shared__ float sbuf[4][64];        // [wave][hc] -> reciprocal of neighbor-sum
    __shared__ int   adjb[4][16];

    const int wv = threadIdx.x >> 6;
    const int lane = threadIdx.x & 63;
    const int n = blockIdx.x * 4 + wv;

    if (lane < 16) adjb[wv][lane] = adj[n * 16 + lane];
    __syncthreads();

    const int e4 = lane >> 2;       // which neighbor row this lane loads
    const int part = lane & 3;      // which quarter of the row
    const int nb = adjb[wv][e4];

    {
        const float* qrow = qt + (size_t)nb * 64;
#pragma unroll
        for (int i = 0; i < 4; i++) {
            int col = part * 4 + i * 16;
            *reinterpret_cast<float4*>(&qbuf[wv][e4][col]) =
                *reinterpret_cast<const float4*>(qrow + col);
        }
        const float* hrow = hW + (size_t)nb * 128;
#pragma unroll
        for (int i = 0; i < 8; i++) {
            int col = part * 4 + i * 16;
            *reinterpret_cast<float4*>(&hbuf[wv][e4][col]) =
                *reinterpret_cast<const float4*>(hrow + col);
        }
    }
    __syncthreads();

    // per-(h,c) neighbor sum -> store reciprocal
    {
        float s = 0.f;
#pragma unroll
        for (int e = 0; e < 16; e++) s += qbuf[wv][e][lane];
        sbuf[wv][lane] = 1.f / s;
    }
    __syncthreads();

    // head-weighted w + softmax over e (rows of 16 spread over 4 lanes, xor-reduce)
    {
        const float hc0 = headConv[0], hc1 = headConv[1], hc2 = headConv[2], hc3 = headConv[3];
        const int c = lane & 15, eg = lane >> 4;
        float wr[4];
        float m = -1e30f;
#pragma unroll
        for (int j = 0; j < 4; j++) {
            int e = eg * 4 + j;
            float v;
            v  = hc0 * qbuf[wv][e][ 0 + c] * sbuf[wv][ 0 + c];
            v += hc1 * qbuf[wv][e][16 + c] * sbuf[wv][16 + c];
            v += hc2 * qbuf[wv][e][32 + c] * sbuf[wv][32 + c];
            v += hc3 * qbuf[wv][e][48 + c] * sbuf[wv][48 + c];
            wr[j] = v;
            m = fmaxf(m, v);
        }
        m = fmaxf(m, __shfl_xor(m, 16));
        m = fmaxf(m, __shfl_xor(m, 32));
        float sum = 0.f;
#pragma unroll
        for (int j = 0; j < 4; j++) { wr[j] = __expf(wr[j] - m); sum += wr[j]; }
        sum += __shfl_xor(sum, 16);
        sum += __shfl_xor(sum, 32);
        float inv = 1.f / sum;
#pragma unroll
        for (int j = 0; j < 4; j++) wbuf[wv][eg * 4 + j][c] = wr[j] * inv;
    }
    __syncthreads();

    // out tile: lane covers 4 c's x 8 d's
    {
        const int dg = lane & 15, cg = lane >> 4;
        const int d0 = dg * 8;
        float bv[8];
        *reinterpret_cast<float4*>(bv)     = *reinterpret_cast<const float4*>(b21 + d0);
        *reinterpret_cast<float4*>(bv + 4) = *reinterpret_cast<const float4*>(b21 + d0 + 4);
        float accv[4][8];
#pragma unroll
        for (int jc = 0; jc < 4; jc++)
#pragma unroll
            for (int j = 0; j < 8; j++) accv[jc][j] = bv[j];

#pragma unroll
        for (int e = 0; e < 16; e++) {
            float hv[8];
            *reinterpret_cast<float4*>(hv)     = *reinterpret_cast<const float4*>(&hbuf[wv][e][d0]);
            *reinterpret_cast<float4*>(hv + 4) = *reinterpret_cast<const float4*>(&hbuf[wv][e][d0 + 4]);
#pragma unroll
            for (int jc = 0; jc < 4; jc++) {
                float wvv = wbuf[wv][e][cg * 4 + jc];
#pragma unroll
                for (int j = 0; j < 8; j++) accv[jc][j] = fmaf(wvv, hv[j], accv[jc][j]);
            }
        }
#pragma unroll
        for (int jc = 0; jc < 4; jc++) {
            float o[8];
#pragma unroll
            for (int j = 0; j < 8; j++) o[j] = leaky_f(accv[jc][j]);
            float* dst = out1 + ((size_t)(n * 16 + cg * 4 + jc)) * 128 + d0;
            *reinterpret_cast<float4*>(dst)     = *reinterpret_cast<const float4*>(o);
            *reinterpret_cast<float4*>(dst + 4) = *reinterpret_cast<const float4*>(o + 4);
        }
    }
}

extern "C" void kernel_launch(void* const* d_in, const int* in_sizes, int n_in,
                              void* d_out, int out_size, void* d_ws, size_t ws_size,
                              hipStream_t stream)
{
    const float* x_node   = (const float*)d_in[0];
    const int*   adj      = (const int*)  d_in[1];
    // d_in[2] = epoch (unused by reference)
    const float* W1       = (const float*)d_in[3];
    const float* b1       = (const float*)d_in[4];
    const float* W2       = (const float*)d_in[5];
    const float* b2       = (const float*)d_in[6];
    const float* W21      = (const float*)d_in[7];
    const float* b21      = (const float*)d_in[8];
    const float* cent     = (const float*)d_in[9];
    const float* headConv = (const float*)d_in[10];

    const int N = in_sizes[0] / 256;     // 20000

    float* out  = (float*)d_out;
    float* h    = out;                       // h_prime: output 0, [N][128]
    float* out1 = out + (size_t)N * 128;     // new_feat: [N][16][128]

    float* ws  = (float*)d_ws;
    float* x   = ws;                         // [N][128]
    float* hW  = x  + (size_t)N * 128;       // [N][128] = h @ W21^T
    float* qt  = hW + (size_t)N * 128;       // [N][64]  = q transposed per node
    float* hn2 = qt + (size_t)N * 64;        // [N]
    float* cn2 = hn2 + N;                    // [64]

    const int mt = (N + 63) / 64;

    // x = leaky(x_node @ W1^T + b1)
    gemm_f32<64, 128, 16, 4, 8, 0><<<mt, 256, 0, stream>>>(x_node, W1, b1, x, N, 256, nullptr, nullptr);
    // h = leaky(x @ W2^T + b2)   (written directly into d_out)
    gemm_f32<64, 128, 16, 4, 8, 0><<<mt, 256, 0, stream>>>(x, W2, b2, h, N, 128, nullptr, nullptr);
    // hW = h @ W21^T  (no bias / act; linearity lets us push W21 before the neighbor mix)
    gemm_f32<64, 128, 16, 4, 8, 1><<<mt, 256, 0, stream>>>(h, W21, nullptr, hW, N, 128, nullptr, nullptr);
    // row norms
    norms_kernel<<<(N + 64 + 3) / 4, 256, 0, stream>>>(h, cent, hn2, cn2, N);
    // q[n][hc] = 1 / (1 + cn2 + hn2 - 2 * h.cent)
    gemm_f32<64, 64, 16, 4, 4, 2><<<mt, 256, 0, stream>>>(h, cent, nullptr, qt, N, 128, hn2, cn2);
    // per-node neighborhood aggregation + final activation
    agg_kernel<<<N / 4, 256, 0, stream>>>(adj, qt, hW, b21, headConv, out1);
}

// Round 2
// 128.209 us; speedup vs baseline: 1.1986x; 1.1986x over previous
//
#include <hip/hip_runtime.h>
#include <cstdint>
#include <cstddef>

#define NEG_SLOPE 0.2f

__device__ __forceinline__ float leaky_f(float x) { return x >= 0.f ? x : NEG_SLOPE * x; }

typedef __attribute__((ext_vector_type(8))) short bf16x8;
typedef __attribute__((ext_vector_type(4))) float f32x4;

__device__ __forceinline__ short f2bf(float f) {
    union { float f; uint32_t u; } v; v.f = f;
    uint32_t r = (v.u + 0x7fffu + ((v.u >> 16) & 1u)) >> 16;
    return (short)r;
}

// -------------------- MFMA bf16 GEMM: C = act(A @ W^T [+ b]) --------------------
// A [M,KK] f32 row-major (converted to bf16 while staging), W [BN,KK] f32 row-major.
// MODE 0: C0 = leaky(acc + bias[col]), width BN=128
// MODE 2: B = [B0(128 rows); B1(64 rows)]; cols<128 -> C0=acc (hW);
//         cols>=128 -> C1 = 1/(1 + cn2[c] + hn2[row] - 2*acc)  (q), width 64
template<int BN, int KK, int MODE>
__global__ __launch_bounds__(256)
void mfma_gemm(const float* __restrict__ A, const float* __restrict__ B0,
               const float* __restrict__ B1, const float* __restrict__ bias,
               float* __restrict__ C0, float* __restrict__ C1,
               const float* __restrict__ hn2, const float* __restrict__ cn2,
               int M)
{
    constexpr int BM = 64;
    constexpr int KP = 40;          // padded K-step row stride (bf16): 80B = 20 banks
    constexpr int NF = BN / 16;     // column fragments per wave

    __shared__ short As[BM * KP];
    __shared__ short Bs[BN * KP];

    const int tid  = threadIdx.x;
    const int wv   = tid >> 6;
    const int lane = tid & 63;
    const int rowBlk = blockIdx.x * BM;

    f32x4 acc[NF];
#pragma unroll
    for (int f = 0; f < NF; f++) acc[f] = f32x4{0.f, 0.f, 0.f, 0.f};

    // fragment addressing: consistent (lane-group, reg) -> k mapping for A and B,
    // so any HW k-permutation cancels in the contraction.
    const int arow = wv * 16 + (lane & 15);
    const int kb   = (lane >> 4) * 8;

    for (int k0 = 0; k0 < KK; k0 += 32) {
        // stage A tile (BM x 32), f32 -> bf16
#pragma unroll
        for (int qi = tid; qi < BM * 8; qi += 256) {
            int r = qi >> 3, kq = qi & 7;
            float4 v = make_float4(0.f, 0.f, 0.f, 0.f);
            int gr = rowBlk + r;
            if (gr < M) v = *reinterpret_cast<const float4*>(A + (size_t)gr * KK + k0 + kq * 4);
            short4 s4 = make_short4(f2bf(v.x), f2bf(v.y), f2bf(v.z), f2bf(v.w));
            *reinterpret_cast<short4*>(&As[r * KP + kq * 4]) = s4;
        }
        // stage B tile (BN x 32), f32 -> bf16 (weights, always in bounds)
#pragma unroll
        for (int qi = tid; qi < BN * 8; qi += 256) {
            int r = qi >> 3, kq = qi & 7;
            const float* src;
            if (MODE == 2 && r >= 128) src = B1 + (size_t)(r - 128) * KK + k0 + kq * 4;
            else                       src = B0 + (size_t)r * KK + k0 + kq * 4;
            float4 v = *reinterpret_cast<const float4*>(src);
            short4 s4 = make_short4(f2bf(v.x), f2bf(v.y), f2bf(v.z), f2bf(v.w));
            *reinterpret_cast<short4*>(&Bs[r * KP + kq * 4]) = s4;
        }
        __syncthreads();

        bf16x8 af = *reinterpret_cast<const bf16x8*>(&As[arow * KP + kb]);
#pragma unroll
        for (int f = 0; f < NF; f++) {
            bf16x8 bfr = *reinterpret_cast<const bf16x8*>(&Bs[(f * 16 + (lane & 15)) * KP + kb]);
            acc[f] = __builtin_amdgcn_mfma_f32_16x16x32_bf16(af, bfr, acc[f], 0, 0, 0);
        }
        __syncthreads();
    }

    // epilogue: D col = lane&15, row = (lane>>4)*4 + j  [m89-verified layout]
    const int crow0 = rowBlk + wv * 16 + (lane >> 4) * 4;
    const int ccol  = lane & 15;
#pragma unroll
    for (int f = 0; f < NF; f++) {
        int col = f * 16 + ccol;
#pragma unroll
        for (int j = 0; j < 4; j++) {
            int row = crow0 + j;
            if (row >= M) continue;
            float v = acc[f][j];
            if (MODE == 0) {
                C0[(size_t)row * 128 + col] = leaky_f(v + bias[col]);
            } else {
                if (col < 128) {
                    C0[(size_t)row * 128 + col] = v;
                } else {
                    int c2 = col - 128;
                    C1[(size_t)row * 64 + c2] = 1.f / (1.f + cn2[c2] + hn2[row] - 2.f * v);
                }
            }
        }
    }
}

// -------------------- row squared-norms: hn2[N] from h, cn2[64] from centroids --------------------
__global__ __launch_bounds__(256)
void norms_kernel(const float* __restrict__ h, const float* __restrict__ cent,
                  float* __restrict__ hn2, float* __restrict__ cn2, int N)
{
    const int wv = threadIdx.x >> 6;
    const int lane = threadIdx.x & 63;
    const int row = blockIdx.x * 4 + wv;
    const int total = N + 64;
    if (row >= total) return;
    const float* src = (row < N) ? (h + (size_t)row * 128) : (cent + (size_t)(row - N) * 128);
    float a = src[lane], b = src[lane + 64];
    float s = fmaf(a, a, b * b);
#pragma unroll
    for (int off = 32; off > 0; off >>= 1) s += __shfl_xor(s, off);
    if (lane == 0) {
        if (row < N) hn2[row] = s; else cn2[row - N] = s;
    }
}

// -------------------- per-node aggregation: one wave per node --------------------
__global__ __launch_bounds__(256)
void agg_kernel(const int* __restrict__ adj, const float* __restrict__ qt,
                const float* __restrict__ hW, const float* __restrict__ b21,
                const float* __restrict__ headConv, float* __restrict__ out1)
{
    __shared__ float qbuf[4][16][68];    // [wave][e][hc] (+pad)
    __shared__ float hbuf[4][16][136];   // [wave][e][d]  (+pad)
    __shared__ float wbuf[4][16][16];    // [wave][e][c]
    __shared__ float sbuf[4][64];        // [wave][hc] -> reciprocal of neighbor-sum
    __shared__ int   adjb[4][16];

    const int wv = threadIdx.x >> 6;
    const int lane = threadIdx.x & 63;
    const int n = blockIdx.x * 4 + wv;

    if (lane < 16) adjb[wv][lane] = adj[n * 16 + lane];
    __syncthreads();

    const int e4 = lane >> 2;
    const int part = lane & 3;
    const int nb = adjb[wv][e4];

    {
        const float* qrow = qt + (size_t)nb * 64;
#pragma unroll
        for (int i = 0; i < 4; i++) {
            int col = part * 4 + i * 16;
            *reinterpret_cast<float4*>(&qbuf[wv][e4][col]) =
                *reinterpret_cast<const float4*>(qrow + col);
        }
        const float* hrow = hW + (size_t)nb * 128;
#pragma unroll
        for (int i = 0; i < 8; i++) {
            int col = part * 4 + i * 16;
            *reinterpret_cast<float4*>(&hbuf[wv][e4][col]) =
                *reinterpret_cast<const float4*>(hrow + col);
        }
    }
    __syncthreads();

    {
        float s = 0.f;
#pragma unroll
        for (int e = 0; e < 16; e++) s += qbuf[wv][e][lane];
        sbuf[wv][lane] = 1.f / s;
    }
    __syncthreads();

    {
        const float hc0 = headConv[0], hc1 = headConv[1], hc2 = headConv[2], hc3 = headConv[3];
        const int c = lane & 15, eg = lane >> 4;
        float wr[4];
        float m = -1e30f;
#pragma unroll
        for (int j = 0; j < 4; j++) {
            int e = eg * 4 + j;
            float v;
            v  = hc0 * qbuf[wv][e][ 0 + c] * sbuf[wv][ 0 + c];
            v += hc1 * qbuf[wv][e][16 + c] * sbuf[wv][16 + c];
            v += hc2 * qbuf[wv][e][32 + c] * sbuf[wv][32 + c];
            v += hc3 * qbuf[wv][e][48 + c] * sbuf[wv][48 + c];
            wr[j] = v;
            m = fmaxf(m, v);
        }
        m = fmaxf(m, __shfl_xor(m, 16));
        m = fmaxf(m, __shfl_xor(m, 32));
        float sum = 0.f;
#pragma unroll
        for (int j = 0; j < 4; j++) { wr[j] = __expf(wr[j] - m); sum += wr[j]; }
        sum += __shfl_xor(sum, 16);
        sum += __shfl_xor(sum, 32);
        float inv = 1.f / sum;
#pragma unroll
        for (int j = 0; j < 4; j++) wbuf[wv][eg * 4 + j][c] = wr[j] * inv;
    }
    __syncthreads();

    {
        const int dg = lane & 15, cg = lane >> 4;
        const int d0 = dg * 8;
        float bv[8];
        *reinterpret_cast<float4*>(bv)     = *reinterpret_cast<const float4*>(b21 + d0);
        *reinterpret_cast<float4*>(bv + 4) = *reinterpret_cast<const float4*>(b21 + d0 + 4);
        float accv[4][8];
#pragma unroll
        for (int jc = 0; jc < 4; jc++)
#pragma unroll
            for (int j = 0; j < 8; j++) accv[jc][j] = bv[j];

#pragma unroll
        for (int e = 0; e < 16; e++) {
            float hv[8];
            *reinterpret_cast<float4*>(hv)     = *reinterpret_cast<const float4*>(&hbuf[wv][e][d0]);
            *reinterpret_cast<float4*>(hv + 4) = *reinterpret_cast<const float4*>(&hbuf[wv][e][d0 + 4]);
#pragma unroll
            for (int jc = 0; jc < 4; jc++) {
                float wvv = wbuf[wv][e][cg * 4 + jc];
#pragma unroll
                for (int j = 0; j < 8; j++) accv[jc][j] = fmaf(wvv, hv[j], accv[jc][j]);
            }
        }
#pragma unroll
        for (int jc = 0; jc < 4; jc++) {
            float o[8];
#pragma unroll
            for (int j = 0; j < 8; j++) o[j] = leaky_f(accv[jc][j]);
            float* dst = out1 + ((size_t)(n * 16 + cg * 4 + jc)) * 128 + d0;
            *reinterpret_cast<float4*>(dst)     = *reinterpret_cast<const float4*>(o);
            *reinterpret_cast<float4*>(dst + 4) = *reinterpret_cast<const float4*>(o + 4);
        }
    }
}

extern "C" void kernel_launch(void* const* d_in, const int* in_sizes, int n_in,
                              void* d_out, int out_size, void* d_ws, size_t ws_size,
                              hipStream_t stream)
{
    const float* x_node   = (const float*)d_in[0];
    const int*   adj      = (const int*)  d_in[1];
    const float* W1       = (const float*)d_in[3];
    const float* b1       = (const float*)d_in[4];
    const float* W2       = (const float*)d_in[5];
    const float* b2       = (const float*)d_in[6];
    const float* W21      = (const float*)d_in[7];
    const float* b21      = (const float*)d_in[8];
    const float* cent     = (const float*)d_in[9];
    const float* headConv = (const float*)d_in[10];

    const int N = in_sizes[0] / 256;     // 20000

    float* out  = (float*)d_out;
    float* h    = out;                       // h_prime: output 0, [N][128]
    float* out1 = out + (size_t)N * 128;     // new_feat: [N][16][128]

    float* ws  = (float*)d_ws;
    float* x   = ws;                         // [N][128]
    float* hW  = x  + (size_t)N * 128;       // [N][128] = h @ W21^T
    float* qt  = hW + (size_t)N * 128;       // [N][64]
    float* hn2 = qt + (size_t)N * 64;        // [N]
    float* cn2 = hn2 + N;                    // [64]

    const int mt = (N + 63) / 64;

    // x = leaky(x_node @ W1^T + b1)
    mfma_gemm<128, 256, 0><<<mt, 256, 0, stream>>>(x_node, W1, nullptr, b1, x, nullptr, nullptr, nullptr, N);
    // h = leaky(x @ W2^T + b2)  (d_out)
    mfma_gemm<128, 128, 0><<<mt, 256, 0, stream>>>(x, W2, nullptr, b2, h, nullptr, nullptr, nullptr, N);
    // row norms (needs h before q-part)
    norms_kernel<<<(N + 64 + 3) / 4, 256, 0, stream>>>(h, cent, hn2, cn2, N);
    // fused: hW = h @ W21^T ; qt = 1/(1 + cn2 + hn2 - 2 * h.cent)
    mfma_gemm<192, 128, 2><<<mt, 256, 0, stream>>>(h, W21, cent, nullptr, hW, qt, hn2, cn2, N);
    // per-node neighborhood aggregation + final activation
    agg_kernel<<<N / 4, 256, 0, stream>>>(adj, qt, hW, b21, headConv, out1);
}

// Round 3
// 96.099 us; speedup vs baseline: 1.5990x; 1.3341x over previous
//
#include <hip/hip_runtime.h>
#include <cstdint>
#include <cstddef>

#define NEG_SLOPE 0.2f

__device__ __forceinline__ float leaky_f(float x) { return x >= 0.f ? x : NEG_SLOPE * x; }

typedef __attribute__((ext_vector_type(8))) short bf16x8;
typedef __attribute__((ext_vector_type(4))) float f32x4;

__device__ __forceinline__ short f2bf(float f) {
    union { float f; uint32_t u; } v; v.f = f;
    uint32_t r = (v.u + 0x7fffu + ((v.u >> 16) & 1u)) >> 16;
    return (short)r;
}

__device__ __forceinline__ void nt_store4(float* p, f32x4 v) {
    __builtin_nontemporal_store(v, reinterpret_cast<f32x4*>(p));
}

// ==================== fused: x=leaky(x_node@W1^T+b1); h=leaky(x@W2^T+b2);
//                      hn2/cn2; hW=h@W21^T; qt=1/(1+cn2+hn2-2*h.cent) ====================
// One 64-row block does the whole chain; x lives only in LDS (bf16), h is written
// once (nt) and kept in LDS (bf16). 8 waves: rowg = wave&3 (16 rows), colg = wave>>2.
__global__ __launch_bounds__(512)
void fused_gemms(const float* __restrict__ x_node,
                 const float* __restrict__ W1, const float* __restrict__ b1,
                 const float* __restrict__ W2, const float* __restrict__ b2,
                 const float* __restrict__ W21, const float* __restrict__ cent,
                 float* __restrict__ h_out, float* __restrict__ hW,
                 float* __restrict__ qt, int M)
{
    __shared__ short As[64 * 40];     // 5.1 KB  (A k-step tile)
    __shared__ short Bs[192 * 40];    // 15.4 KB (B k-step tile, max 192 rows)
    __shared__ short Xs[64 * 136];    // 17.4 KB (x, then h; bf16, padded stride)
    __shared__ float cn2s[64];
    __shared__ float hn2s[2][64];

    const int tid  = threadIdx.x;
    const int wave = tid >> 6;
    const int lane = tid & 63;
    const int rowg = wave & 3;
    const int colg = wave >> 2;
    const int rowBlk = blockIdx.x * 64;

    const int arow   = rowg * 16 + (lane & 15);   // A-frag local row
    const int kb     = (lane >> 4) * 8;           // k sub-block
    const int crow_l = rowg * 16 + (lane >> 4) * 4; // C local row base

    // ---- cn2 (redundant per block, cheap): 8 threads per centroid row ----
    {
        int r = tid >> 3, c0 = (tid & 7) * 16;
        const float* cr = cent + (size_t)r * 128 + c0;
        float s = 0.f;
#pragma unroll
        for (int q = 0; q < 4; q++) {
            float4 v = *reinterpret_cast<const float4*>(cr + q * 4);
            s += v.x * v.x + v.y * v.y + v.z * v.z + v.w * v.w;
        }
        s += __shfl_xor(s, 1); s += __shfl_xor(s, 2); s += __shfl_xor(s, 4);
        if ((lane & 7) == 0) cn2s[r] = s;
    }

    // ---- Phase 1: x = leaky(x_node @ W1^T + b1), K=256 ----
    f32x4 acc[6];
#pragma unroll
    for (int f = 0; f < 4; f++) acc[f] = f32x4{0.f, 0.f, 0.f, 0.f};

    for (int k0 = 0; k0 < 256; k0 += 32) {
        {   // stage A (64x32)
            int r = tid >> 3, kq = tid & 7;
            int gr = rowBlk + r;
            float4 v = make_float4(0.f, 0.f, 0.f, 0.f);
            if (gr < M) v = *reinterpret_cast<const float4*>(x_node + (size_t)gr * 256 + k0 + kq * 4);
            *reinterpret_cast<short4*>(&As[r * 40 + kq * 4]) =
                make_short4(f2bf(v.x), f2bf(v.y), f2bf(v.z), f2bf(v.w));
        }
#pragma unroll
        for (int it = 0; it < 2; it++) {   // stage B = W1 (128x32)
            int idx = tid + it * 512;
            int r = idx >> 3, kq = idx & 7;
            float4 v = *reinterpret_cast<const float4*>(W1 + (size_t)r * 256 + k0 + kq * 4);
            *reinterpret_cast<short4*>(&Bs[r * 40 + kq * 4]) =
                make_short4(f2bf(v.x), f2bf(v.y), f2bf(v.z), f2bf(v.w));
        }
        __syncthreads();
        bf16x8 af = *reinterpret_cast<const bf16x8*>(&As[arow * 40 + kb]);
#pragma unroll
        for (int f = 0; f < 4; f++) {
            bf16x8 bfr = *reinterpret_cast<const bf16x8*>(&Bs[(colg * 64 + f * 16 + (lane & 15)) * 40 + kb]);
            acc[f] = __builtin_amdgcn_mfma_f32_16x16x32_bf16(af, bfr, acc[f], 0, 0, 0);
        }
        __syncthreads();
    }
    // epilogue -> Xs (bf16 x-tile)
#pragma unroll
    for (int f = 0; f < 4; f++) {
        int col = colg * 64 + f * 16 + (lane & 15);
        float bv = b1[col];
#pragma unroll
        for (int j = 0; j < 4; j++)
            Xs[(crow_l + j) * 136 + col] = f2bf(leaky_f(acc[f][j] + bv));
    }

    // ---- Phase 2: h = leaky(x @ W2^T + b2), K=128, A=Xs ----
#pragma unroll
    for (int f = 0; f < 4; f++) acc[f] = f32x4{0.f, 0.f, 0.f, 0.f};
    for (int k0 = 0; k0 < 128; k0 += 32) {
#pragma unroll
        for (int it = 0; it < 2; it++) {
            int idx = tid + it * 512;
            int r = idx >> 3, kq = idx & 7;
            float4 v = *reinterpret_cast<const float4*>(W2 + (size_t)r * 128 + k0 + kq * 4);
            *reinterpret_cast<short4*>(&Bs[r * 40 + kq * 4]) =
                make_short4(f2bf(v.x), f2bf(v.y), f2bf(v.z), f2bf(v.w));
        }
        __syncthreads();
        bf16x8 af = *reinterpret_cast<const bf16x8*>(&Xs[arow * 136 + k0 + kb]);
#pragma unroll
        for (int f = 0; f < 4; f++) {
            bf16x8 bfr = *reinterpret_cast<const bf16x8*>(&Bs[(colg * 64 + f * 16 + (lane & 15)) * 40 + kb]);
            acc[f] = __builtin_amdgcn_mfma_f32_16x16x32_bf16(af, bfr, acc[f], 0, 0, 0);
        }
        __syncthreads();
    }
    // epilogue: h -> global (nt) + hn2 partials + Xs (bf16 h-tile)
    {
        float hv[4][4];
#pragma unroll
        for (int f = 0; f < 4; f++) {
            int col = colg * 64 + f * 16 + (lane & 15);
            float bv = b2[col];
#pragma unroll
            for (int j = 0; j < 4; j++) {
                float x = leaky_f(acc[f][j] + bv);
                hv[f][j] = x;
                int gr = rowBlk + crow_l + j;
                if (gr < M) __builtin_nontemporal_store(x, &h_out[(size_t)gr * 128 + col]);
            }
        }
#pragma unroll
        for (int j = 0; j < 4; j++) {
            float s = 0.f;
#pragma unroll
            for (int f = 0; f < 4; f++) s = fmaf(hv[f][j], hv[f][j], s);
            s += __shfl_xor(s, 1); s += __shfl_xor(s, 2);
            s += __shfl_xor(s, 4); s += __shfl_xor(s, 8);
            if ((lane & 15) == 0) hn2s[colg][crow_l + j] = s;
        }
#pragma unroll
        for (int f = 0; f < 4; f++) {
            int col = colg * 64 + f * 16 + (lane & 15);
#pragma unroll
            for (int j = 0; j < 4; j++)
                Xs[(crow_l + j) * 136 + col] = f2bf(hv[f][j]);
        }
    }

    // ---- Phase 3: [hW | q] = h @ [W21;cent]^T, K=128, 192 cols ----
#pragma unroll
    for (int f = 0; f < 6; f++) acc[f] = f32x4{0.f, 0.f, 0.f, 0.f};
    for (int k0 = 0; k0 < 128; k0 += 32) {
#pragma unroll
        for (int it = 0; it < 3; it++) {
            int idx = tid + it * 512;
            int r = idx >> 3, kq = idx & 7;
            const float* src = (r < 128) ? (W21 + (size_t)r * 128 + k0 + kq * 4)
                                         : (cent + (size_t)(r - 128) * 128 + k0 + kq * 4);
            float4 v = *reinterpret_cast<const float4*>(src);
            *reinterpret_cast<short4*>(&Bs[r * 40 + kq * 4]) =
                make_short4(f2bf(v.x), f2bf(v.y), f2bf(v.z), f2bf(v.w));
        }
        __syncthreads();
        bf16x8 af = *reinterpret_cast<const bf16x8*>(&Xs[arow * 136 + k0 + kb]);
#pragma unroll
        for (int f = 0; f < 6; f++) {
            bf16x8 bfr = *reinterpret_cast<const bf16x8*>(&Bs[(colg * 96 + f * 16 + (lane & 15)) * 40 + kb]);
            acc[f] = __builtin_amdgcn_mfma_f32_16x16x32_bf16(af, bfr, acc[f], 0, 0, 0);
        }
        __syncthreads();
    }
#pragma unroll
    for (int f = 0; f < 6; f++) {
        int col = colg * 96 + f * 16 + (lane & 15);
#pragma unroll
        for (int j = 0; j < 4; j++) {
            int gr = rowBlk + crow_l + j;
            if (gr >= M) continue;
            float v = acc[f][j];
            if (col < 128) {
                hW[(size_t)gr * 128 + col] = v;
            } else {
                int c2 = col - 128;
                float hn2 = hn2s[0][crow_l + j] + hn2s[1][crow_l + j];
                qt[(size_t)gr * 64 + c2] = 1.f / (1.f + cn2s[c2] + hn2 - 2.f * v);
            }
        }
    }
}

// ==================== per-node aggregation: one wave per node ====================
// Linear (conflict-free) LDS staging; nt stores for the 164 MB output.
__global__ __launch_bounds__(256)
void agg_kernel(const int* __restrict__ adj, const float* __restrict__ qt,
                const float* __restrict__ hW, const float* __restrict__ b21,
                const float* __restrict__ headConv, float* __restrict__ out1)
{
    __shared__ float qs[4][1024];        // [wave][e*64 + hc]
    __shared__ float hs[4][2048];        // [wave][e*128 + d]
    __shared__ float wbuf[4][16][16];    // [wave][e][c]
    __shared__ float sbuf[4][64];        // [wave][hc] reciprocal neighbor-sum
    __shared__ int   adjb[4][16];

    const int wv = threadIdx.x >> 6;
    const int lane = threadIdx.x & 63;
    const int n = blockIdx.x * 4 + wv;

    if (lane < 16) adjb[wv][lane] = adj[n * 16 + lane];
    __syncthreads();

    // stage q: chunk i covers rows 4i..4i+3; lane l -> linear float4 slot l
#pragma unroll
    for (int i = 0; i < 4; i++) {
        int row = i * 4 + (lane >> 4), col = (lane & 15) * 4;
        const float* src = qt + (size_t)adjb[wv][row] * 64 + col;
        *reinterpret_cast<float4*>(&qs[wv][i * 256 + lane * 4]) =
            *reinterpret_cast<const float4*>(src);
    }
    // stage hW: chunk i covers rows 2i,2i+1; 32 lanes per full 512B row
#pragma unroll
    for (int i = 0; i < 8; i++) {
        int row = i * 2 + (lane >> 5), col = (lane & 31) * 4;
        const float* src = hW + (size_t)adjb[wv][row] * 128 + col;
        *reinterpret_cast<float4*>(&hs[wv][i * 256 + lane * 4]) =
            *reinterpret_cast<const float4*>(src);
    }
    __syncthreads();

    // per-(h,c) neighbor sum -> reciprocal
    {
        float s = 0.f;
#pragma unroll
        for (int e = 0; e < 16; e++) s += qs[wv][e * 64 + lane];
        sbuf[wv][lane] = 1.f / s;
    }
    __syncthreads();

    // head-weighted w + softmax over e
    {
        const float hc0 = headConv[0], hc1 = headConv[1], hc2 = headConv[2], hc3 = headConv[3];
        const int c = lane & 15, eg = lane >> 4;
        float wr[4];
        float m = -1e30f;
#pragma unroll
        for (int j = 0; j < 4; j++) {
            int e = eg * 4 + j;
            float v;
            v  = hc0 * qs[wv][e * 64 +  0 + c] * sbuf[wv][ 0 + c];
            v += hc1 * qs[wv][e * 64 + 16 + c] * sbuf[wv][16 + c];
            v += hc2 * qs[wv][e * 64 + 32 + c] * sbuf[wv][32 + c];
            v += hc3 * qs[wv][e * 64 + 48 + c] * sbuf[wv][48 + c];
            wr[j] = v;
            m = fmaxf(m, v);
        }
        m = fmaxf(m, __shfl_xor(m, 16));
        m = fmaxf(m, __shfl_xor(m, 32));
        float sum = 0.f;
#pragma unroll
        for (int j = 0; j < 4; j++) { wr[j] = __expf(wr[j] - m); sum += wr[j]; }
        sum += __shfl_xor(sum, 16);
        sum += __shfl_xor(sum, 32);
        float inv = 1.f / sum;
#pragma unroll
        for (int j = 0; j < 4; j++) wbuf[wv][eg * 4 + j][c] = wr[j] * inv;
    }
    __syncthreads();

    // out tile: lane (cg,dg) covers c = cg*4+jc, d = dg*4..+3 and +64
    {
        const int dg = lane & 15, cg = lane >> 4;
        const int d0 = dg * 4;
        float bv[8];
        *reinterpret_cast<float4*>(bv)     = *reinterpret_cast<const float4*>(b21 + d0);
        *reinterpret_cast<float4*>(bv + 4) = *reinterpret_cast<const float4*>(b21 + d0 + 64);
        float accv[4][8];
#pragma unroll
        for (int jc = 0; jc < 4; jc++)
#pragma unroll
            for (int j = 0; j < 8; j++) accv[jc][j] = bv[j];

#pragma unroll
        for (int e = 0; e < 16; e++) {
            float hv[8];
            *reinterpret_cast<float4*>(hv)     = *reinterpret_cast<const float4*>(&hs[wv][e * 128 + d0]);
            *reinterpret_cast<float4*>(hv + 4) = *reinterpret_cast<const float4*>(&hs[wv][e * 128 + d0 + 64]);
#pragma unroll
            for (int jc = 0; jc < 4; jc++) {
                float wvv = wbuf[wv][e][cg * 4 + jc];
#pragma unroll
                for (int j = 0; j < 8; j++) accv[jc][j] = fmaf(wvv, hv[j], accv[jc][j]);
            }
        }
#pragma unroll
        for (int jc = 0; jc < 4; jc++) {
            f32x4 lo, hi;
#pragma unroll
            for (int j = 0; j < 4; j++) { lo[j] = leaky_f(accv[jc][j]); hi[j] = leaky_f(accv[jc][j + 4]); }
            float* dst = out1 + ((size_t)(n * 16 + cg * 4 + jc)) * 128;
            nt_store4(dst + d0, lo);
            nt_store4(dst + d0 + 64, hi);
        }
    }
}

extern "C" void kernel_launch(void* const* d_in, const int* in_sizes, int n_in,
                              void* d_out, int out_size, void* d_ws, size_t ws_size,
                              hipStream_t stream)
{
    const float* x_node   = (const float*)d_in[0];
    const int*   adj      = (const int*)  d_in[1];
    const float* W1       = (const float*)d_in[3];
    const float* b1       = (const float*)d_in[4];
    const float* W2       = (const float*)d_in[5];
    const float* b2       = (const float*)d_in[6];
    const float* W21      = (const float*)d_in[7];
    const float* b21      = (const float*)d_in[8];
    const float* cent     = (const float*)d_in[9];
    const float* headConv = (const float*)d_in[10];

    const int N = in_sizes[0] / 256;     // 20000

    float* out  = (float*)d_out;
    float* h    = out;                       // h_prime: output 0, [N][128]
    float* out1 = out + (size_t)N * 128;     // new_feat: [N][16][128]

    float* ws  = (float*)d_ws;
    float* hW  = ws;                         // [N][128] = h @ W21^T
    float* qt  = hW + (size_t)N * 128;       // [N][64]

    const int mt = (N + 63) / 64;

    fused_gemms<<<mt, 512, 0, stream>>>(x_node, W1, b1, W2, b2, W21, cent, h, hW, qt, N);
    agg_kernel<<<N / 4, 256, 0, stream>>>(adj, qt, hW, b21, headConv, out1);
}

// Round 4
// 68.575 us; speedup vs baseline: 2.2408x; 1.4014x over previous
//
#include <hip/hip_runtime.h>
#include <cstdint>
#include <cstddef>

#define NEG_SLOPE 0.2f

typedef __attribute__((ext_vector_type(8))) short bf16x8;
typedef __attribute__((ext_vector_type(8))) unsigned short u16x8;
typedef __attribute__((ext_vector_type(4))) float f32x4;

__device__ __forceinline__ float leaky_f(float x) { return x >= 0.f ? x : NEG_SLOPE * x; }

__device__ __forceinline__ unsigned short f2bf(float f) {
    union { float f; uint32_t u; } v; v.f = f;
    return (unsigned short)((v.u + 0x7fffu + ((v.u >> 16) & 1u)) >> 16);
}
__device__ __forceinline__ float bf2f(unsigned short u) {
    union { uint32_t u; float f; } v; v.u = ((uint32_t)u) << 16; return v.f;
}
__device__ __forceinline__ float bfhi(uint32_t w) {   // high bf16 of a packed pair
    union { uint32_t u; float f; } v; v.u = w & 0xffff0000u; return v.f;
}
__device__ __forceinline__ float bflo(uint32_t w) {   // low bf16 of a packed pair
    union { uint32_t u; float f; } v; v.u = w << 16; return v.f;
}
__device__ __forceinline__ u16x8 cvt8(float4 a, float4 b) {
    u16x8 o;
    o[0] = f2bf(a.x); o[1] = f2bf(a.y); o[2] = f2bf(a.z); o[3] = f2bf(a.w);
    o[4] = f2bf(b.x); o[5] = f2bf(b.y); o[6] = f2bf(b.z); o[7] = f2bf(b.w);
    return o;
}

// ==================== pack: weights -> fragment-ready bf16; x_node -> bf16; cn2 ====================
// Fragment layout: frag(step,f) = 64 lanes x 8 bf16, element (lane) = W[f*16+(lane&15)][step*32+(lane>>4)*8+j]
__global__ __launch_bounds__(256)
void pack_kernel(const float* __restrict__ x_node, const float* __restrict__ W1,
                 const float* __restrict__ W2, const float* __restrict__ W21,
                 const float* __restrict__ cent,
                 unsigned short* __restrict__ xb, unsigned short* __restrict__ pw1,
                 unsigned short* __restrict__ pw2, unsigned short* __restrict__ pw3,
                 float* __restrict__ cn2g, int N)
{
    const int bid = blockIdx.x, tid = threadIdx.x;
    if (bid < 36) {                       // 144 weight fragments, 4 per block
        const int sub = tid >> 6, lane = tid & 63, g = bid * 4 + sub;
        const int l15 = lane & 15, l4 = lane >> 4;
        const float* src; unsigned short* dst;
        if (g < 64) {        // W1: 8 steps x 8 frags, K=256
            int step = g >> 3, f = g & 7;
            src = W1 + (size_t)(f * 16 + l15) * 256 + step * 32 + l4 * 8;
            dst = pw1 + ((size_t)(step * 8 + f) * 64 + lane) * 8;
        } else if (g < 96) { // W2: 4 steps x 8 frags, K=128
            int gg = g - 64, step = gg >> 3, f = gg & 7;
            src = W2 + (size_t)(f * 16 + l15) * 128 + step * 32 + l4 * 8;
            dst = pw2 + ((size_t)(step * 8 + f) * 64 + lane) * 8;
        } else {             // [W21;cent]: 4 steps x 12 frags, K=128
            int gg = g - 96, step = gg / 12, f = gg % 12;
            int brow = f * 16 + l15;
            const float* base = (brow < 128) ? (W21 + (size_t)brow * 128)
                                             : (cent + (size_t)(brow - 128) * 128);
            src = base + step * 32 + l4 * 8;
            dst = pw3 + ((size_t)(step * 12 + f) * 64 + lane) * 8;
        }
        float4 a = *reinterpret_cast<const float4*>(src);
        float4 b = *reinterpret_cast<const float4*>(src + 4);
        *reinterpret_cast<u16x8*>(dst) = cvt8(a, b);
    } else if (bid == 36) {               // cn2
        int r = tid >> 2, c0 = (tid & 3) * 32;
        const float* cr = cent + (size_t)r * 128 + c0;
        float s = 0.f;
#pragma unroll
        for (int q = 0; q < 8; q++) {
            float4 v = *reinterpret_cast<const float4*>(cr + q * 4);
            s += v.x * v.x + v.y * v.y + v.z * v.z + v.w * v.w;
        }
        s += __shfl_xor(s, 1); s += __shfl_xor(s, 2);
        if ((tid & 3) == 0) cn2g[r] = s;
    } else {                              // x_node -> bf16, 4096 elems/block
        size_t base = (size_t)(bid - 37) * 4096 + (size_t)tid * 16;
        float4 v0 = *reinterpret_cast<const float4*>(x_node + base);
        float4 v1 = *reinterpret_cast<const float4*>(x_node + base + 4);
        float4 v2 = *reinterpret_cast<const float4*>(x_node + base + 8);
        float4 v3 = *reinterpret_cast<const float4*>(x_node + base + 12);
        *reinterpret_cast<u16x8*>(xb + base)     = cvt8(v0, v1);
        *reinterpret_cast<u16x8*>(xb + base + 8) = cvt8(v2, v3);
    }
}

// ==================== fused GEMM chain: 16 rows/block, 4 waves (col-split) ====================
// B fragments load straight from packed global (no LDS); A from xb / Xs LDS. 3 barriers total.
__global__ __launch_bounds__(256)
void fused_gemms(const unsigned short* __restrict__ xb,
                 const unsigned short* __restrict__ pw1, const unsigned short* __restrict__ pw2,
                 const unsigned short* __restrict__ pw3,
                 const float* __restrict__ b1, const float* __restrict__ b2,
                 const float* __restrict__ cn2g,
                 float* __restrict__ h_out, unsigned short* __restrict__ hWb,
                 unsigned short* __restrict__ qtb, int N)
{
    __shared__ __align__(16) short Xs[16 * 136];   // x, then h (bf16, padded stride)
    __shared__ float hn2s[4][16];

    const int tid = threadIdx.x, wave = tid >> 6, lane = tid & 63;
    const int l15 = lane & 15, l4 = lane >> 4;
    const int rowBlk = blockIdx.x * 16;

    // ---- Phase 1: x = leaky(x_node @ W1^T + b1), K=256, waves split 128 cols in 4x32 ----
    f32x4 a0{0.f,0.f,0.f,0.f}, a1{0.f,0.f,0.f,0.f}, a2{0.f,0.f,0.f,0.f};
    {
        const unsigned short* ap = xb + (size_t)(rowBlk + l15) * 256 + l4 * 8;
        const unsigned short* bp = pw1 + (size_t)(wave * 2) * 512 + lane * 8;
#pragma unroll
        for (int k = 0; k < 8; k++) {
            bf16x8 af = *reinterpret_cast<const bf16x8*>(ap + k * 32);
            bf16x8 bf0 = *reinterpret_cast<const bf16x8*>(bp + (size_t)k * 8 * 512);
            bf16x8 bf1 = *reinterpret_cast<const bf16x8*>(bp + (size_t)k * 8 * 512 + 512);
            a0 = __builtin_amdgcn_mfma_f32_16x16x32_bf16(af, bf0, a0, 0, 0, 0);
            a1 = __builtin_amdgcn_mfma_f32_16x16x32_bf16(af, bf1, a1, 0, 0, 0);
        }
        float bia = b1[wave * 32 + l15], bib = b1[wave * 32 + 16 + l15];
#pragma unroll
        for (int j = 0; j < 4; j++) {
            Xs[(l4 * 4 + j) * 136 + wave * 32 + l15]      = (short)f2bf(leaky_f(a0[j] + bia));
            Xs[(l4 * 4 + j) * 136 + wave * 32 + 16 + l15] = (short)f2bf(leaky_f(a1[j] + bib));
        }
    }
    __syncthreads();

    // ---- Phase 2: h = leaky(x @ W2^T + b2), K=128 ----
    a0 = f32x4{0.f,0.f,0.f,0.f}; a1 = f32x4{0.f,0.f,0.f,0.f};
    const short* xp = &Xs[l15 * 136 + l4 * 8];
    {
        const unsigned short* bp = pw2 + (size_t)(wave * 2) * 512 + lane * 8;
#pragma unroll
        for (int k = 0; k < 4; k++) {
            bf16x8 af = *reinterpret_cast<const bf16x8*>(xp + k * 32);
            bf16x8 bf0 = *reinterpret_cast<const bf16x8*>(bp + (size_t)k * 8 * 512);
            bf16x8 bf1 = *reinterpret_cast<const bf16x8*>(bp + (size_t)k * 8 * 512 + 512);
            a0 = __builtin_amdgcn_mfma_f32_16x16x32_bf16(af, bf0, a0, 0, 0, 0);
            a1 = __builtin_amdgcn_mfma_f32_16x16x32_bf16(af, bf1, a1, 0, 0, 0);
        }
    }
    float hv0[4], hv1[4], pn[4];
    {
        float bia = b2[wave * 32 + l15], bib = b2[wave * 32 + 16 + l15];
#pragma unroll
        for (int j = 0; j < 4; j++) {
            hv0[j] = leaky_f(a0[j] + bia);
            hv1[j] = leaky_f(a1[j] + bib);
            float s = hv0[j] * hv0[j] + hv1[j] * hv1[j];
            s += __shfl_xor(s, 1); s += __shfl_xor(s, 2);
            s += __shfl_xor(s, 4); s += __shfl_xor(s, 8);
            pn[j] = s;
        }
    }
    __syncthreads();   // all waves done reading Xs(x)
#pragma unroll
    for (int j = 0; j < 4; j++) {
        int gr = rowBlk + l4 * 4 + j;
        __builtin_nontemporal_store(hv0[j], &h_out[(size_t)gr * 128 + wave * 32 + l15]);
        __builtin_nontemporal_store(hv1[j], &h_out[(size_t)gr * 128 + wave * 32 + 16 + l15]);
        Xs[(l4 * 4 + j) * 136 + wave * 32 + l15]      = (short)f2bf(hv0[j]);
        Xs[(l4 * 4 + j) * 136 + wave * 32 + 16 + l15] = (short)f2bf(hv1[j]);
        if (l15 == 0) hn2s[wave][l4 * 4 + j] = pn[j];
    }
    __syncthreads();

    // ---- Phase 3: [hW | q] = h @ [W21;cent]^T, K=128, 192 cols in 4x48 ----
    a0 = f32x4{0.f,0.f,0.f,0.f}; a1 = f32x4{0.f,0.f,0.f,0.f}; a2 = f32x4{0.f,0.f,0.f,0.f};
    {
        const unsigned short* bp = pw3 + (size_t)(wave * 3) * 512 + lane * 8;
#pragma unroll
        for (int k = 0; k < 4; k++) {
            bf16x8 af = *reinterpret_cast<const bf16x8*>(xp + k * 32);
            bf16x8 bf0 = *reinterpret_cast<const bf16x8*>(bp + (size_t)k * 12 * 512);
            bf16x8 bf1 = *reinterpret_cast<const bf16x8*>(bp + (size_t)k * 12 * 512 + 512);
            bf16x8 bf2 = *reinterpret_cast<const bf16x8*>(bp + (size_t)k * 12 * 512 + 1024);
            a0 = __builtin_amdgcn_mfma_f32_16x16x32_bf16(af, bf0, a0, 0, 0, 0);
            a1 = __builtin_amdgcn_mfma_f32_16x16x32_bf16(af, bf1, a1, 0, 0, 0);
            a2 = __builtin_amdgcn_mfma_f32_16x16x32_bf16(af, bf2, a2, 0, 0, 0);
        }
    }
    {
        float hn2r[4];
#pragma unroll
        for (int j = 0; j < 4; j++)
            hn2r[j] = hn2s[0][l4 * 4 + j] + hn2s[1][l4 * 4 + j]
                    + hn2s[2][l4 * 4 + j] + hn2s[3][l4 * 4 + j];
        f32x4 av[3] = {a0, a1, a2};
#pragma unroll
        for (int ff = 0; ff < 3; ff++) {
            int col = wave * 48 + ff * 16 + l15;
            if (col < 128) {
#pragma unroll
                for (int j = 0; j < 4; j++) {
                    int gr = rowBlk + l4 * 4 + j;
                    hWb[(size_t)gr * 128 + col] = f2bf(av[ff][j]);
                }
            } else {
                int c2 = col - 128;
                float cn2v = cn2g[c2];
#pragma unroll
                for (int j = 0; j < 4; j++) {
                    int gr = rowBlk + l4 * 4 + j;
                    float q = 1.f / (1.f + cn2v + hn2r[j] - 2.f * av[ff][j]);
                    qtb[(size_t)gr * 64 + c2] = f2bf(q);
                }
            }
        }
    }
}

// ==================== per-node aggregation: one wave per node, bf16 tables ====================
__global__ __launch_bounds__(256)
void agg_kernel(const int* __restrict__ adj, const unsigned short* __restrict__ qtb,
                const unsigned short* __restrict__ hWb, const float* __restrict__ b21,
                const float* __restrict__ headConv, float* __restrict__ out1)
{
    __shared__ __align__(16) unsigned short qs[4][16 * 64];
    __shared__ __align__(16) unsigned short hs[4][16 * 128];
    __shared__ float wbuf[4][16][16];

    const int wv = threadIdx.x >> 6, lane = threadIdx.x & 63;
    const int n = blockIdx.x * 4 + wv;

    int myadj = adj[n * 16 + (lane & 15)];

    // stage q (16 rows x 128B) and hW (16 rows x 256B), linear LDS, conflict-free
#pragma unroll
    for (int i = 0; i < 2; i++) {
        int row = i * 8 + (lane >> 3);
        int nb = __shfl(myadj, row);
        *reinterpret_cast<u16x8*>(&qs[wv][i * 512 + lane * 8]) =
            *reinterpret_cast<const u16x8*>(qtb + (size_t)nb * 64 + (lane & 7) * 8);
    }
#pragma unroll
    for (int i = 0; i < 4; i++) {
        int row = i * 4 + (lane >> 4);
        int nb = __shfl(myadj, row);
        *reinterpret_cast<u16x8*>(&hs[wv][i * 512 + lane * 8]) =
            *reinterpret_cast<const u16x8*>(hWb + (size_t)nb * 128 + (lane & 15) * 8);
    }
    __syncthreads();

    // lane = hc: neighbor-sum + head-weighted logits + in-register softmax
    {
        float qv[16];
        float s = 0.f;
#pragma unroll
        for (int e = 0; e < 16; e++) { qv[e] = bf2f(qs[wv][e * 64 + lane]); s += qv[e]; }
        float rs = 1.f / s;
        float conv = headConv[lane >> 4];
        float wn[16], m = -1e30f;
#pragma unroll
        for (int e = 0; e < 16; e++) {
            float t = conv * qv[e] * rs;
            t += __shfl_xor(t, 16);
            t += __shfl_xor(t, 32);       // all lanes now hold w_logit[c][e]
            wn[e] = t;
            m = fmaxf(m, t);
        }
        float sum = 0.f;
#pragma unroll
        for (int e = 0; e < 16; e++) { wn[e] = __expf(wn[e] - m); sum += wn[e]; }
        float inv = 1.f / sum;
        const int c = lane & 15, eg = lane >> 4;
#pragma unroll
        for (int j = 0; j < 4; j++) wbuf[wv][eg * 4 + j][c] = wn[eg * 4 + j] * inv;
    }
    __syncthreads();

    // out tile: lane (cg,dg) covers c = cg*4+jc, d = dg*4..+3 and +64..+67
    {
        const int dg = lane & 15, cg = lane >> 4, d0 = dg * 4;
        float bv[8];
        *reinterpret_cast<float4*>(bv)     = *reinterpret_cast<const float4*>(b21 + d0);
        *reinterpret_cast<float4*>(bv + 4) = *reinterpret_cast<const float4*>(b21 + d0 + 64);
        float acc[4][8];
#pragma unroll
        for (int jc = 0; jc < 4; jc++)
#pragma unroll
            for (int j = 0; j < 8; j++) acc[jc][j] = bv[j];

#pragma unroll
        for (int e = 0; e < 16; e++) {
            uint2 wlo = *reinterpret_cast<const uint2*>(&hs[wv][e * 128 + d0]);
            uint2 whi = *reinterpret_cast<const uint2*>(&hs[wv][e * 128 + 64 + d0]);
            float hv[8];
            hv[0] = bflo(wlo.x); hv[1] = bfhi(wlo.x); hv[2] = bflo(wlo.y); hv[3] = bfhi(wlo.y);
            hv[4] = bflo(whi.x); hv[5] = bfhi(whi.x); hv[6] = bflo(whi.y); hv[7] = bfhi(whi.y);
#pragma unroll
            for (int jc = 0; jc < 4; jc++) {
                float w = wbuf[wv][e][cg * 4 + jc];
#pragma unroll
                for (int j = 0; j < 8; j++) acc[jc][j] = fmaf(w, hv[j], acc[jc][j]);
            }
        }
#pragma unroll
        for (int jc = 0; jc < 4; jc++) {
            f32x4 lo, hi;
#pragma unroll
            for (int j = 0; j < 4; j++) { lo[j] = leaky_f(acc[jc][j]); hi[j] = leaky_f(acc[jc][j + 4]); }
            float* dst = out1 + ((size_t)(n * 16 + cg * 4 + jc)) * 128;
            __builtin_nontemporal_store(lo, reinterpret_cast<f32x4*>(dst + d0));
            __builtin_nontemporal_store(hi, reinterpret_cast<f32x4*>(dst + d0 + 64));
        }
    }
}

extern "C" void kernel_launch(void* const* d_in, const int* in_sizes, int n_in,
                              void* d_out, int out_size, void* d_ws, size_t ws_size,
                              hipStream_t stream)
{
    const float* x_node   = (const float*)d_in[0];
    const int*   adj      = (const int*)  d_in[1];
    const float* W1       = (const float*)d_in[3];
    const float* b1       = (const float*)d_in[4];
    const float* W2       = (const float*)d_in[5];
    const float* b2       = (const float*)d_in[6];
    const float* W21      = (const float*)d_in[7];
    const float* b21      = (const float*)d_in[8];
    const float* cent     = (const float*)d_in[9];
    const float* headConv = (const float*)d_in[10];

    const int N = in_sizes[0] / 256;     // 20000

    float* h    = (float*)d_out;                 // h_prime [N][128]
    float* out1 = h + (size_t)N * 128;           // new_feat [N][16][128]

    unsigned short* xb  = (unsigned short*)d_ws;       // [N][256] bf16
    unsigned short* hWb = xb  + (size_t)N * 256;       // [N][128] bf16
    unsigned short* qtb = hWb + (size_t)N * 128;       // [N][64]  bf16
    unsigned short* pw1 = qtb + (size_t)N * 64;        // 32768
    unsigned short* pw2 = pw1 + 32768;                 // 16384
    unsigned short* pw3 = pw2 + 16384;                 // 24576
    float*          cn2g = (float*)(pw3 + 24576);      // [64]

    const int xblocks = (N * 256) / 4096;              // 1250

    pack_kernel<<<37 + xblocks, 256, 0, stream>>>(x_node, W1, W2, W21, cent,
                                                  xb, pw1, pw2, pw3, cn2g, N);
    fused_gemms<<<N / 16, 256, 0, stream>>>(xb, pw1, pw2, pw3, b1, b2, cn2g,
                                            h, hWb, qtb, N);
    agg_kernel<<<N / 4, 256, 0, stream>>>(adj, qtb, hWb, b21, headConv, out1);
}